// Round 1
// 542.153 us; speedup vs baseline: 1.1297x; 1.1297x over previous
//
#include <hip/hip_runtime.h>

#define IN_DIM 4096
#define OUT_DIM 4096
#define N_ROWS 8192
#define RANK 256

typedef __bf16 bf16x8 __attribute__((ext_vector_type(8)));
typedef float f32x4 __attribute__((ext_vector_type(4)));
typedef unsigned short u16;
typedef unsigned short u16x4 __attribute__((ext_vector_type(4)));

__device__ __forceinline__ u16 f2b(float f) {
    unsigned int u = __builtin_bit_cast(unsigned int, f);
    unsigned int r = u + 0x7FFFu + ((u >> 16) & 1u);
    return (u16)(r >> 16);
}

__device__ __forceinline__ void async16(const void* g, const void* l) {
    __builtin_amdgcn_global_load_lds(
        (const __attribute__((address_space(1))) void*)g,
        (__attribute__((address_space(3))) void*)l, 16, 0, 0);
}

// fp32 -> bf16 bulk convert, 4 elems/thread, coalesced.
__global__ __launch_bounds__(256) void cvt4(const float* __restrict__ s,
                                            u16* __restrict__ d, int n4) {
    int i = blockIdx.x * 256 + threadIdx.x;
    if (i >= n4) return;
    f32x4 v = __builtin_nontemporal_load((const f32x4*)s + i);
    u16x4 o;
    o.x = f2b(v.x); o.y = f2b(v.y); o.z = f2b(v.z); o.w = f2b(v.w);
    *((u16x4*)d + i) = o;
}

// AdT[i][r] = bf16(d[r] * A[r][i])
__global__ __launch_bounds__(256) void vera_adt(const float* __restrict__ A,
                                                const float* __restrict__ d,
                                                u16* __restrict__ adt) {
    int r = threadIdx.x;
    int i0 = blockIdx.x * 64;
    float dv = d[r];
    const float* ap = A + (size_t)r * IN_DIM + i0;
#pragma unroll 4
    for (int j = 0; j < 64; ++j)
        adt[(size_t)(i0 + j) * RANK + r] = f2b(__builtin_nontemporal_load(ap + j) * dv);
}

// ---------------------------------------------------------------------------
// 128^2-tile m97-structure GEMM, kept ONLY for the small K=256 W_eff pass.
// MODE 0: out(u16)[row][col] = bf16(W[row][col] + bvec[row] * acc)
// ---------------------------------------------------------------------------
template <int MODE, int K, int NN, int TM, int TN>
__global__ __launch_bounds__(256) void vera_gemm(
    const u16* __restrict__ Aop, const u16* __restrict__ Bop,
    const float* __restrict__ W, const float* __restrict__ bvec,
    void* __restrict__ outv) {
    __shared__ __align__(16) __bf16 As[128 * 32];
    __shared__ __align__(16) __bf16 Bs[128 * 32];

    const int tid = threadIdx.x;
    const int lane = tid & 63;
    const int wavei = __builtin_amdgcn_readfirstlane(tid >> 6);
    const int fr = lane & 15;
    const int fq = lane >> 4;
    const int wm = (wavei >> 1) * 64;
    const int wn = (wavei & 1) * 64;

    constexpr int G = 8;
    const int bid = blockIdx.x;
    const int g = bid / (G * TN);
    const int r = bid - g * (G * TN);
    const int bm = (g * G + (r & (G - 1))) * 128;
    const int bn = (r / G) * 128;

    const int srow = tid >> 2;
    const int sk = (tid & 3) * 8;
    const u16* ga0 = Aop + (size_t)(bm + srow) * K + sk;
    const u16* ga1 = Aop + (size_t)(bm + 64 + srow) * K + sk;
    const u16* gb0 = Bop + (size_t)(bn + srow) * K + sk;
    const u16* gb1 = Bop + (size_t)(bn + 64 + srow) * K + sk;

    char* lAs = (char*)As;
    char* lBs = (char*)Bs;
    const int lo = wavei * 1024;

    f32x4 acc[4][4] = {};

    for (int k0 = 0; k0 < K; k0 += 32) {
        __syncthreads();
        async16(ga0 + k0, lAs + lo);
        async16(ga1 + k0, lAs + 4096 + lo);
        async16(gb0 + k0, lBs + lo);
        async16(gb1 + k0, lBs + 4096 + lo);
        __syncthreads();

        const __bf16* ap = As + (wm + fr) * 32 + fq * 8;
        const __bf16* bp = Bs + (wn + fr) * 32 + fq * 8;
        bf16x8 af[4], bfr[4];
#pragma unroll
        for (int i = 0; i < 4; ++i) {
            af[i] = *(const bf16x8*)(ap + i * 16 * 32);
            bfr[i] = *(const bf16x8*)(bp + i * 16 * 32);
        }
#pragma unroll
        for (int mi = 0; mi < 4; ++mi)
#pragma unroll
            for (int ni = 0; ni < 4; ++ni)
                acc[mi][ni] = __builtin_amdgcn_mfma_f32_16x16x32_bf16(
                    af[mi], bfr[ni], acc[mi][ni], 0, 0, 0);
    }

#pragma unroll
    for (int ni = 0; ni < 4; ++ni) {
        const int col = bn + wn + ni * 16 + fr;
        float bcol = (MODE == 1) ? bvec[col] : 0.f;
#pragma unroll
        for (int mi = 0; mi < 4; ++mi) {
            const int row0 = bm + wm + mi * 16 + fq * 4;
#pragma unroll
            for (int v = 0; v < 4; ++v) {
                const int row = row0 + v;
                float a = acc[mi][ni][v];
                if (MODE == 0) {
                    float wv = __builtin_nontemporal_load(&W[(size_t)row * NN + col]);
                    ((u16*)outv)[(size_t)row * NN + col] = f2b(wv + bvec[row] * a);
                } else {
                    __builtin_nontemporal_store(a + bcol,
                        &((float*)outv)[(size_t)row * NN + col]);
                }
            }
        }
    }
}

// ---------------------------------------------------------------------------
// 256x256 8-phase counted-vmcnt GEMM (T2+T3+T4+T5), for the main pass.
// C[M][N] = Aop[M][K] . Bop[N][K]^T, out f32 = acc + bvec[col], nt store.
//
// 512 thr = 8 waves (2M x 4N); per wave 128x64 out = acc[8][4] of 16x16 frags.
// LDS 128 KiB: per operand 4 slots of [256 rows][32 k] bf16 (16 KiB each);
// slot(tile,j) = (tile&1)*2 + j  (j = K-half of the BK=64 step).
//
// Swizzle (T2, rule #21 both-sides): within a row (4 chunks of 16B), physical
// chunk = logical ^ ((row>>1)&3). global_load_lds writes linearly, so the
// per-lane GLOBAL source is pre-inverse-swizzled; ds_read applies the same
// involution. Read conflict <= 2-way (free, m136).
//
// Per iteration (computes tiles t,t+1; stages t+1 tail / t+2 / t+3 head):
//   P1 rd A(t,k0)mh0+B(t,k0)  st B(t+1,k0)->Bs2   mfma mh0
//   P2 rd A(t,k0)mh1          st A(t+1,k1)->As3   mfma mh1  vmcnt(6)
//   P3 rd A(t,k1)mh0+B(t,k1)  st B(t+1,k1)->Bs3   mfma mh0
//   P4 rd A(t,k1)mh1          st A(t+2,k0)->As0   mfma mh1  vmcnt(6)
//   P5 rd A(t1,k0)mh0+B(t1,k0) st B(t+2,k0)->Bs0  mfma mh0
//   P6 rd A(t1,k0)mh1         st A(t+2,k1)->As1   mfma mh1  vmcnt(6)
//   P7 rd A(t1,k1)mh0+B(t1,k1) st B(t+2,k1)->Bs1  mfma mh0
//   P8 rd A(t1,k1)mh1         st A(t+3,k0)->As2   mfma mh1  vmcnt(6)
// Ledger (per wave, 2 loads/stage): each vmcnt(6) drains exactly the 2
// oldest halves = the pair first-read 1 phase later; 3 halves stay in
// flight. Every slot is rewritten >=2 barriers after its last read.
// Tail: t+2/t+3 clamped to NTK-1 -> stages target slots never read again
// (addresses stay in bounds; counts stay uniform).
// ---------------------------------------------------------------------------
#define BARW() do { __builtin_amdgcn_s_barrier(); \
    asm volatile("s_waitcnt lgkmcnt(0)" ::: "memory"); \
    __builtin_amdgcn_sched_barrier(0); } while (0)
#define W6()   asm volatile("s_waitcnt vmcnt(6)" ::: "memory")
#define ENDP() __builtin_amdgcn_s_barrier()

template <int K, int MT, int NTL>
__global__ __launch_bounds__(512, 2) void gemm256(
    const u16* __restrict__ Aop, const u16* __restrict__ Bop,
    const float* __restrict__ bvec, float* __restrict__ out) {
    constexpr int NTK = K / 64;
    __shared__ __align__(16) char lds[131072];
    char* const L = (char*)lds;

    const int tid = threadIdx.x;
    const int lane = tid & 63;
    const int wavei = __builtin_amdgcn_readfirstlane(tid >> 6);
    const int fr = lane & 15;
    const int fq = lane >> 4;
    const int wmi = wavei >> 2;   // 0..1
    const int wni = wavei & 3;    // 0..3

    // XCD-bijective swizzle (NWG % 8 == 0), M innermost within an XCD chunk
    constexpr int NWG = MT * NTL;
    const int bid = blockIdx.x;
    const int idx = (bid & 7) * (NWG / 8) + (bid >> 3);
    const int bm = (idx % MT) * 256;
    const int bn = (idx / MT) * 256;

    // --- staging: thread covers 16B chunks c0 = wavei*128+lane and c0+64.
    // chunk c -> (row = c>>2, pchunk = c&3); source k-chunk pre-inverse-swz.
    const int c0 = wavei * 128 + lane;
    const int r0 = c0 >> 2;
    const int k0of = ((c0 & 3) ^ ((r0 >> 1) & 3)) * 8;
    const int c1 = c0 + 64;
    const int r1 = c1 >> 2;
    const int k1of = ((c1 & 3) ^ ((r1 >> 1) & 3)) * 8;
    const u16* gA0 = Aop + (size_t)(bm + r0) * K + k0of;
    const u16* gA1 = Aop + (size_t)(bm + r1) * K + k1of;
    const u16* gB0 = Bop + (size_t)(bn + r0) * K + k0of;
    const u16* gB1 = Bop + (size_t)(bn + r1) * K + k1of;
    const int wl = wavei * 2048;  // wave-uniform LDS base; HW adds lane*16

    auto stageA = [&](int tau, int j, int slot) {
        const int kb = tau * 64 + j * 32;
        async16(gA0 + kb, L + slot * 16384 + wl);
        async16(gA1 + kb, L + slot * 16384 + wl + 1024);
    };
    auto stageB = [&](int tau, int j, int slot) {
        const int kb = tau * 64 + j * 32;
        async16(gB0 + kb, L + 65536 + slot * 16384 + wl);
        async16(gB1 + kb, L + 65536 + slot * 16384 + wl + 1024);
    };

    // --- compute-side ds_read bases (swizzled chunk; row bits1-2 == fr bits1-2)
    const int aswz = ((fq ^ ((fr >> 1) & 3)) << 4);
    const int aoff = (wmi * 128 + fr) * 64 + aswz;
    const int boff = 65536 + (wni * 64 + fr) * 64 + aswz;

    bf16x8 af[4], bf[4];
    f32x4 acc[8][4] = {};

    auto ldA = [&](int slot, int mh) {
        const char* p = L + slot * 16384 + aoff + mh * 4096;
#pragma unroll
        for (int i = 0; i < 4; ++i) af[i] = *(const bf16x8*)(p + i * 1024);
    };
    auto ldB = [&](int slot) {
        const char* p = L + slot * 16384 + boff;
#pragma unroll
        for (int i = 0; i < 4; ++i) bf[i] = *(const bf16x8*)(p + i * 1024);
    };
    auto MF = [&](int mh) {
        __builtin_amdgcn_s_setprio(1);
#pragma unroll
        for (int mi = 0; mi < 4; ++mi)
#pragma unroll
            for (int ni = 0; ni < 4; ++ni)
                acc[mh * 4 + mi][ni] = __builtin_amdgcn_mfma_f32_16x16x32_bf16(
                    af[mi], bf[ni], acc[mh * 4 + mi][ni], 0, 0, 0);
        __builtin_amdgcn_s_setprio(0);
    };

    // prologue: A00,B00,A01,B01,A10 (10 loads); vmcnt(6) -> A00,B00 landed
    stageA(0, 0, 0); stageB(0, 0, 0);
    stageA(0, 1, 1); stageB(0, 1, 1);
    stageA(1, 0, 2);
    asm volatile("s_waitcnt vmcnt(6)" ::: "memory");
    __builtin_amdgcn_s_barrier();

#pragma unroll 1
    for (int it = 0; it < NTK / 2; ++it) {
        const int t  = 2 * it;
        const int t1 = t + 1;
        const int t2 = (t + 2 < NTK) ? t + 2 : NTK - 1;
        const int t3 = (t + 3 < NTK) ? t + 3 : NTK - 1;

        ldA(0, 0); ldB(0); stageB(t1, 0, 2); BARW(); MF(0); ENDP();          // P1
        ldA(0, 1);         stageA(t1, 1, 3); BARW(); MF(1); W6(); ENDP();    // P2
        ldA(1, 0); ldB(1); stageB(t1, 1, 3); BARW(); MF(0); ENDP();          // P3
        ldA(1, 1);         stageA(t2, 0, 0); BARW(); MF(1); W6(); ENDP();    // P4
        ldA(2, 0); ldB(2); stageB(t2, 0, 0); BARW(); MF(0); ENDP();          // P5
        ldA(2, 1);         stageA(t2, 1, 1); BARW(); MF(1); W6(); ENDP();    // P6
        ldA(3, 0); ldB(3); stageB(t2, 1, 1); BARW(); MF(0); ENDP();          // P7
        ldA(3, 1);         stageA(t3, 0, 2); BARW(); MF(1); W6(); ENDP();    // P8
    }

    // drain tail stages before epilogue
    asm volatile("s_waitcnt vmcnt(0)" ::: "memory");

    // C/D layout (m89): col = lane&15, row = (lane>>4)*4 + reg
    const int colb = bn + wni * 64 + fr;
    const int rowb = bm + wmi * 128 + fq * 4;
#pragma unroll
    for (int ni = 0; ni < 4; ++ni) {
        const int col = colb + ni * 16;
        const float bc = bvec[col];
#pragma unroll
        for (int m8 = 0; m8 < 8; ++m8) {
            const int row = rowb + (m8 >> 2) * 64 + (m8 & 3) * 16;
#pragma unroll
            for (int v = 0; v < 4; ++v)
                __builtin_nontemporal_store(acc[m8][ni][v] + bc,
                    &out[(size_t)(row + v) * (NTL * 256) + col]);
        }
    }
}

extern "C" void kernel_launch(void* const* d_in, const int* in_sizes, int n_in,
                              void* d_out, int out_size, void* d_ws, size_t ws_size,
                              hipStream_t stream) {
    (void)in_sizes; (void)n_in; (void)out_size; (void)ws_size;
    const float* x    = (const float*)d_in[0];   // [N, IN]
    const float* W    = (const float*)d_in[1];   // [OUT, IN]
    const float* bias = (const float*)d_in[2];   // [OUT]
    const float* A    = (const float*)d_in[3];   // [RANK, IN]
    const float* B    = (const float*)d_in[4];   // [OUT, RANK]
    const float* bv   = (const float*)d_in[5];   // [OUT]
    const float* dv   = (const float*)d_in[6];   // [RANK]

    char* ws = (char*)d_ws;
    u16* xb  = (u16*)ws;                                          // 64 MiB
    u16* wb  = (u16*)(ws + (size_t)N_ROWS * IN_DIM * 2);          // 32 MiB
    u16* adt = (u16*)(ws + (size_t)N_ROWS * IN_DIM * 2
                         + (size_t)OUT_DIM * IN_DIM * 2);         // 2 MiB
    u16* Bb  = adt + (size_t)IN_DIM * RANK;                       // 2 MiB

    // 1) B -> bf16
    cvt4<<<dim3(OUT_DIM * RANK / 4 / 256), 256, 0, stream>>>(B, Bb, OUT_DIM * RANK / 4);
    // 2) AdT = (diag(d) A)^T, bf16
    vera_adt<<<dim3(IN_DIM / 64), 256, 0, stream>>>(A, dv, adt);
    // 3) W_eff = W + diag(b) . B . AdT^T   (M=OUT, N=IN, K=RANK) — small K,
    //    keep the 128^2 kernel
    vera_gemm<0, RANK, IN_DIM, OUT_DIM / 128, IN_DIM / 128>
        <<<dim3((OUT_DIM / 128) * (IN_DIM / 128)), 256, 0, stream>>>(
        Bb, adt, W, bv, wb);
    // 4) x -> bf16
    cvt4<<<dim3(N_ROWS * IN_DIM / 4 / 256), 256, 0, stream>>>(x, xb, N_ROWS * IN_DIM / 4);
    // 5) out = x . W_eff^T + bias   (M=N_ROWS, N=OUT, K=IN) — 256^2 8-phase
    gemm256<IN_DIM, N_ROWS / 256, OUT_DIM / 256>
        <<<dim3((N_ROWS / 256) * (OUT_DIM / 256)), 512, 0, stream>>>(
        xb, wb, bias, (float*)d_out);
}

// Round 2
// 505.418 us; speedup vs baseline: 1.2118x; 1.0727x over previous
//
#include <hip/hip_runtime.h>

#define IN_DIM 4096
#define OUT_DIM 4096
#define N_ROWS 8192
#define RANK 256

typedef __bf16 bf16x8 __attribute__((ext_vector_type(8)));
typedef float f32x4 __attribute__((ext_vector_type(4)));
typedef unsigned short u16;
typedef unsigned short u16x4 __attribute__((ext_vector_type(4)));
typedef unsigned short u16x8 __attribute__((ext_vector_type(8)));

__device__ __forceinline__ u16 f2b(float f) {
    unsigned int u = __builtin_bit_cast(unsigned int, f);
    unsigned int r = u + 0x7FFFu + ((u >> 16) & 1u);
    return (u16)(r >> 16);
}

__device__ __forceinline__ float b2f(u16 s) {
    return __builtin_bit_cast(float, (unsigned int)s << 16);
}

__device__ __forceinline__ void async16(const void* g, const void* l) {
    __builtin_amdgcn_global_load_lds(
        (const __attribute__((address_space(1))) void*)g,
        (__attribute__((address_space(3))) void*)l, 16, 0, 0);
}

// fp32 -> bf16 bulk convert, 4 elems/thread, coalesced.
__global__ __launch_bounds__(256) void cvt4(const float* __restrict__ s,
                                            u16* __restrict__ d, int n4) {
    int i = blockIdx.x * 256 + threadIdx.x;
    if (i >= n4) return;
    f32x4 v = __builtin_nontemporal_load((const f32x4*)s + i);
    u16x4 o;
    o.x = f2b(v.x); o.y = f2b(v.y); o.z = f2b(v.z); o.w = f2b(v.w);
    *((u16x4*)d + i) = o;
}

// AdT[i][r] = bf16(d[r] * A[r][i])
__global__ __launch_bounds__(256) void vera_adt(const float* __restrict__ A,
                                                const float* __restrict__ d,
                                                u16* __restrict__ adt) {
    int r = threadIdx.x;
    int i0 = blockIdx.x * 64;
    float dv = d[r];
    const float* ap = A + (size_t)r * IN_DIM + i0;
#pragma unroll 4
    for (int j = 0; j < 64; ++j)
        adt[(size_t)(i0 + j) * RANK + r] = f2b(__builtin_nontemporal_load(ap + j) * dv);
}

// ---------------------------------------------------------------------------
// 128^2-tile GEMM for the small K=256 W_eff pass only.
// out(u16)[row][col] = bf16(W[row][col] + bvec[row] * acc)
// Epilogue: acc -> bf16 -> LDS [128][128], then coalesced 16B copy-out that
// reads W as f32x4 pairs (replaces 64 scalar 2B stores + scattered 4B loads
// per lane -> fully coalesced).
// ---------------------------------------------------------------------------
template <int K, int NN, int TM, int TN>
__global__ __launch_bounds__(256) void vera_gemm(
    const u16* __restrict__ Aop, const u16* __restrict__ Bop,
    const float* __restrict__ W, const float* __restrict__ bvec,
    u16* __restrict__ outv) {
    __shared__ __align__(16) char smem[32768];   // K-loop: 16 KiB; epi: 32 KiB
    __bf16* As = (__bf16*)smem;
    __bf16* Bs = (__bf16*)(smem + 8192);

    const int tid = threadIdx.x;
    const int lane = tid & 63;
    const int wavei = __builtin_amdgcn_readfirstlane(tid >> 6);
    const int fr = lane & 15;
    const int fq = lane >> 4;
    const int wm = (wavei >> 1) * 64;
    const int wn = (wavei & 1) * 64;

    constexpr int G = 8;
    const int bid = blockIdx.x;
    const int g = bid / (G * TN);
    const int r = bid - g * (G * TN);
    const int bm = (g * G + (r & (G - 1))) * 128;
    const int bn = (r / G) * 128;

    const int srow = tid >> 2;
    const int sk = (tid & 3) * 8;
    const u16* ga0 = Aop + (size_t)(bm + srow) * K + sk;
    const u16* ga1 = Aop + (size_t)(bm + 64 + srow) * K + sk;
    const u16* gb0 = Bop + (size_t)(bn + srow) * K + sk;
    const u16* gb1 = Bop + (size_t)(bn + 64 + srow) * K + sk;

    char* lAs = (char*)As;
    char* lBs = (char*)Bs;
    const int lo = wavei * 1024;

    f32x4 acc[4][4] = {};

    for (int k0 = 0; k0 < K; k0 += 32) {
        __syncthreads();
        async16(ga0 + k0, lAs + lo);
        async16(ga1 + k0, lAs + 4096 + lo);
        async16(gb0 + k0, lBs + lo);
        async16(gb1 + k0, lBs + 4096 + lo);
        __syncthreads();

        const __bf16* ap = As + (wm + fr) * 32 + fq * 8;
        const __bf16* bp = Bs + (wn + fr) * 32 + fq * 8;
        bf16x8 af[4], bfr[4];
#pragma unroll
        for (int i = 0; i < 4; ++i) {
            af[i] = *(const bf16x8*)(ap + i * 16 * 32);
            bfr[i] = *(const bf16x8*)(bp + i * 16 * 32);
        }
#pragma unroll
        for (int mi = 0; mi < 4; ++mi)
#pragma unroll
            for (int ni = 0; ni < 4; ++ni)
                acc[mi][ni] = __builtin_amdgcn_mfma_f32_16x16x32_bf16(
                    af[mi], bfr[ni], acc[mi][ni], 0, 0, 0);
    }

    // ---- epilogue: stage acc (bf16) to LDS, coalesced copy-out with W ----
    __syncthreads();                     // waves may still be reading K-loop LDS
    u16* S = (u16*)smem;                 // [128][128] u16 = 32 KiB
#pragma unroll
    for (int ni = 0; ni < 4; ++ni) {
        const int cl = wn + ni * 16 + fr;
#pragma unroll
        for (int mi = 0; mi < 4; ++mi) {
#pragma unroll
            for (int v = 0; v < 4; ++v) {
                const int rl = wm + mi * 16 + fq * 4 + v;
                S[rl * 128 + cl] = f2b(acc[mi][ni][v]);
            }
        }
    }
    __syncthreads();
#pragma unroll
    for (int j = 0; j < 8; ++j) {
        const int c = tid + j * 256;       // 2048 chunks of 16B
        const int rl = c >> 4;
        const int cl = (c & 15) * 8;
        const int grow = bm + rl;
        const size_t goff = (size_t)grow * NN + (bn + cl);
        u16x8 sv = *(const u16x8*)(S + rl * 128 + cl);
        f32x4 w0 = __builtin_nontemporal_load((const f32x4*)(W + goff));
        f32x4 w1 = __builtin_nontemporal_load((const f32x4*)(W + goff + 4));
        const float bvr = bvec[grow];
        u16x8 o;
        o[0] = f2b(w0.x + bvr * b2f(sv[0]));
        o[1] = f2b(w0.y + bvr * b2f(sv[1]));
        o[2] = f2b(w0.z + bvr * b2f(sv[2]));
        o[3] = f2b(w0.w + bvr * b2f(sv[3]));
        o[4] = f2b(w1.x + bvr * b2f(sv[4]));
        o[5] = f2b(w1.y + bvr * b2f(sv[5]));
        o[6] = f2b(w1.z + bvr * b2f(sv[6]));
        o[7] = f2b(w1.w + bvr * b2f(sv[7]));
        *(u16x8*)(outv + goff) = o;
    }
}

// ---------------------------------------------------------------------------
// 256x256 8-phase counted-vmcnt GEMM (T2+T3+T4+T5), main pass.
// C[M][N] = Aop[M][K] . Bop[N][K]^T, out f32 = acc + bvec[col], nt store.
//
// Block mapping (changed r1->r2): XCD-chunked, N-INNERMOST within chunk.
// Chunk = 64 consecutive idx = 4 bm-rows x all 16 bn. The 16 concurrent
// blocks per bm-row share that A-panel (2 MiB) through the XCD's L2 (16x
// reuse, concurrent, no LLC-timing dependence); wb (32 MiB) is re-touched
// every row-epoch (~20 us) so it stays LLC-resident. Expected FETCH ~=
// xb 64 MiB + wb 32 MiB (was 645 MB with M-innermost: A-panel re-touch
// interval 129 us / 320 MB of stream -> LLC evictions).
//
// Schedule: per phase {ds_read subtile || 1 stage (2x global_load_lds) ->
// barrier -> lgkmcnt(0) -> setprio(1) 16xMFMA setprio(0) -> barrier};
// vmcnt(6) at even phases only (3 half-tiles stay in flight, never drained
// to 0 in the loop). LDS XOR swizzle both-sides (rule #21): linear LDS dest,
// pre-inverse-swizzled global source, same involution on ds_read.
// Measured r1: SQ_LDS_BANK_CONFLICT = 0.
// ---------------------------------------------------------------------------
#define BARW() do { __builtin_amdgcn_s_barrier(); \
    asm volatile("s_waitcnt lgkmcnt(0)" ::: "memory"); \
    __builtin_amdgcn_sched_barrier(0); } while (0)
#define W6()   asm volatile("s_waitcnt vmcnt(6)" ::: "memory")
#define ENDP() __builtin_amdgcn_s_barrier()

template <int K, int MT, int NTL>
__global__ __launch_bounds__(512, 2) void gemm256(
    const u16* __restrict__ Aop, const u16* __restrict__ Bop,
    const float* __restrict__ bvec, float* __restrict__ out) {
    constexpr int NTK = K / 64;
    __shared__ __align__(16) char lds[131072];
    char* const L = (char*)lds;

    const int tid = threadIdx.x;
    const int lane = tid & 63;
    const int wavei = __builtin_amdgcn_readfirstlane(tid >> 6);
    const int fr = lane & 15;
    const int fq = lane >> 4;
    const int wmi = wavei >> 2;   // 0..1
    const int wni = wavei & 3;    // 0..3

    // XCD-bijective swizzle (NWG % 8 == 0), N-INNERMOST within chunk
    constexpr int NWG = MT * NTL;
    const int bid = blockIdx.x;
    const int idx = (bid & 7) * (NWG / 8) + (bid >> 3);
    const int bn = (idx % NTL) * 256;
    const int bm = (idx / NTL) * 256;

    // staging: thread covers 16B chunks c0 = wavei*128+lane and c0+64.
    // chunk c -> (row = c>>2, pchunk = c&3); source k-chunk pre-inverse-swz.
    const int c0 = wavei * 128 + lane;
    const int r0 = c0 >> 2;
    const int k0of = ((c0 & 3) ^ ((r0 >> 1) & 3)) * 8;
    const int c1 = c0 + 64;
    const int r1 = c1 >> 2;
    const int k1of = ((c1 & 3) ^ ((r1 >> 1) & 3)) * 8;
    const u16* gA0 = Aop + (size_t)(bm + r0) * K + k0of;
    const u16* gA1 = Aop + (size_t)(bm + r1) * K + k1of;
    const u16* gB0 = Bop + (size_t)(bn + r0) * K + k0of;
    const u16* gB1 = Bop + (size_t)(bn + r1) * K + k1of;
    const int wl = wavei * 2048;  // wave-uniform LDS base; HW adds lane*16

    auto stageA = [&](int tau, int j, int slot) {
        const int kb = tau * 64 + j * 32;
        async16(gA0 + kb, L + slot * 16384 + wl);
        async16(gA1 + kb, L + slot * 16384 + wl + 1024);
    };
    auto stageB = [&](int tau, int j, int slot) {
        const int kb = tau * 64 + j * 32;
        async16(gB0 + kb, L + 65536 + slot * 16384 + wl);
        async16(gB1 + kb, L + 65536 + slot * 16384 + wl + 1024);
    };

    // compute-side ds_read bases (swizzled chunk)
    const int aswz = ((fq ^ ((fr >> 1) & 3)) << 4);
    const int aoff = (wmi * 128 + fr) * 64 + aswz;
    const int boff = 65536 + (wni * 64 + fr) * 64 + aswz;

    bf16x8 af[4], bf[4];
    f32x4 acc[8][4] = {};

    auto ldA = [&](int slot, int mh) {
        const char* p = L + slot * 16384 + aoff + mh * 4096;
#pragma unroll
        for (int i = 0; i < 4; ++i) af[i] = *(const bf16x8*)(p + i * 1024);
    };
    auto ldB = [&](int slot) {
        const char* p = L + slot * 16384 + boff;
#pragma unroll
        for (int i = 0; i < 4; ++i) bf[i] = *(const bf16x8*)(p + i * 1024);
    };
    auto MF = [&](int mh) {
        __builtin_amdgcn_s_setprio(1);
#pragma unroll
        for (int mi = 0; mi < 4; ++mi)
#pragma unroll
            for (int ni = 0; ni < 4; ++ni)
                acc[mh * 4 + mi][ni] = __builtin_amdgcn_mfma_f32_16x16x32_bf16(
                    af[mi], bf[ni], acc[mh * 4 + mi][ni], 0, 0, 0);
        __builtin_amdgcn_s_setprio(0);
    };

    // prologue: A00,B00,A01,B01,A10 (10 loads); vmcnt(6) -> A00,B00 landed
    stageA(0, 0, 0); stageB(0, 0, 0);
    stageA(0, 1, 1); stageB(0, 1, 1);
    stageA(1, 0, 2);
    asm volatile("s_waitcnt vmcnt(6)" ::: "memory");
    __builtin_amdgcn_s_barrier();

#pragma unroll 1
    for (int it = 0; it < NTK / 2; ++it) {
        const int t1 = 2 * it + 1;
        const int t2 = (2 * it + 2 < NTK) ? 2 * it + 2 : NTK - 1;
        const int t3 = (2 * it + 3 < NTK) ? 2 * it + 3 : NTK - 1;

        ldA(0, 0); ldB(0); stageB(t1, 0, 2); BARW(); MF(0); ENDP();          // P1
        ldA(0, 1);         stageA(t1, 1, 3); BARW(); MF(1); W6(); ENDP();    // P2
        ldA(1, 0); ldB(1); stageB(t1, 1, 3); BARW(); MF(0); ENDP();          // P3
        ldA(1, 1);         stageA(t2, 0, 0); BARW(); MF(1); W6(); ENDP();    // P4
        ldA(2, 0); ldB(2); stageB(t2, 0, 0); BARW(); MF(0); ENDP();          // P5
        ldA(2, 1);         stageA(t2, 1, 1); BARW(); MF(1); W6(); ENDP();    // P6
        ldA(3, 0); ldB(3); stageB(t2, 1, 1); BARW(); MF(0); ENDP();          // P7
        ldA(3, 1);         stageA(t3, 0, 2); BARW(); MF(1); W6(); ENDP();    // P8
    }

    // drain tail stages before epilogue
    asm volatile("s_waitcnt vmcnt(0)" ::: "memory");

    // C/D layout (m89): col = lane&15, row = (lane>>4)*4 + reg
    const int colb = bn + wni * 64 + fr;
    const int rowb = bm + wmi * 128 + fq * 4;
#pragma unroll
    for (int ni = 0; ni < 4; ++ni) {
        const int col = colb + ni * 16;
        const float bc = bvec[col];
#pragma unroll
        for (int m8 = 0; m8 < 8; ++m8) {
            const int row = rowb + (m8 >> 2) * 64 + (m8 & 3) * 16;
#pragma unroll
            for (int v = 0; v < 4; ++v)
                __builtin_nontemporal_store(acc[m8][ni][v] + bc,
                    &out[(size_t)(row + v) * (NTL * 256) + col]);
        }
    }
}

extern "C" void kernel_launch(void* const* d_in, const int* in_sizes, int n_in,
                              void* d_out, int out_size, void* d_ws, size_t ws_size,
                              hipStream_t stream) {
    (void)in_sizes; (void)n_in; (void)out_size; (void)ws_size;
    const float* x    = (const float*)d_in[0];   // [N, IN]
    const float* W    = (const float*)d_in[1];   // [OUT, IN]
    const float* bias = (const float*)d_in[2];   // [OUT]
    const float* A    = (const float*)d_in[3];   // [RANK, IN]
    const float* B    = (const float*)d_in[4];   // [OUT, RANK]
    const float* bv   = (const float*)d_in[5];   // [OUT]
    const float* dv   = (const float*)d_in[6];   // [RANK]

    char* ws = (char*)d_ws;
    u16* xb  = (u16*)ws;                                          // 64 MiB
    u16* wb  = (u16*)(ws + (size_t)N_ROWS * IN_DIM * 2);          // 32 MiB
    u16* adt = (u16*)(ws + (size_t)N_ROWS * IN_DIM * 2
                         + (size_t)OUT_DIM * IN_DIM * 2);         // 2 MiB
    u16* Bb  = adt + (size_t)IN_DIM * RANK;                       // 2 MiB

    // 1) B -> bf16
    cvt4<<<dim3(OUT_DIM * RANK / 4 / 256), 256, 0, stream>>>(B, Bb, OUT_DIM * RANK / 4);
    // 2) AdT = (diag(d) A)^T, bf16
    vera_adt<<<dim3(IN_DIM / 64), 256, 0, stream>>>(A, dv, adt);
    // 3) W_eff = W + diag(b) . B . AdT^T   (M=OUT, N=IN, K=RANK)
    vera_gemm<RANK, IN_DIM, OUT_DIM / 128, IN_DIM / 128>
        <<<dim3((OUT_DIM / 128) * (IN_DIM / 128)), 256, 0, stream>>>(
        Bb, adt, W, bv, wb);
    // 4) x -> bf16
    cvt4<<<dim3(N_ROWS * IN_DIM / 4 / 256), 256, 0, stream>>>(x, xb, N_ROWS * IN_DIM / 4);
    // 5) out = x . W_eff^T + bias   (M=N_ROWS, N=OUT, K=IN) — 256^2 8-phase
    gemm256<IN_DIM, N_ROWS / 256, OUT_DIM / 256>
        <<<dim3((N_ROWS / 256) * (OUT_DIM / 256)), 512, 0, stream>>>(
        xb, wb, bias, (float*)d_out);
}